// Round 1
// baseline (1885.347 us; speedup 1.0000x reference)
//
#include <hip/hip_runtime.h>

#define NB_ 16
#define TQ_ 2048
#define TS_ 2048
#define DH_ 1024
#define QB_ 32
#define SB_ 64
#define NT_ 512

typedef _Float16 f16x8 __attribute__((ext_vector_type(8)));
typedef _Float16 f16x4 __attribute__((ext_vector_type(4)));
typedef float f32x4 __attribute__((ext_vector_type(4)));

__device__ inline uint32_t pack_h2(float a, float b) {
  union { _Float16 h[2]; uint32_t u; } c;
  c.h[0] = (_Float16)a; c.h[1] = (_Float16)b;
  return c.u;
}

__global__ void convert_f32_f16(const float* __restrict__ src, _Float16* __restrict__ dst) {
  size_t i = ((size_t)blockIdx.x * blockDim.x + threadIdx.x) * 8;
  float4 v0 = *(const float4*)(src + i);
  float4 v1 = *(const float4*)(src + i + 4);
  f16x8 o;
  o[0] = (_Float16)v0.x; o[1] = (_Float16)v0.y; o[2] = (_Float16)v0.z; o[3] = (_Float16)v0.w;
  o[4] = (_Float16)v1.x; o[5] = (_Float16)v1.y; o[6] = (_Float16)v1.z; o[7] = (_Float16)v1.w;
  *(f16x8*)(dst + i) = o;
}

// LDS layout (bytes):
//   q_base : 0      .. 65536   Q tile 32x1024 f16, swizzled
//   stg0   : 65536  .. 81920   staging buffer A (K chunk 64x128 f16 / Vt chunk 128x64 f16)
//   stg1   : 81920  .. 98304   staging buffer B
//   s_lds  : 98304  .. 107008  S tile 32 x 68 f32 (stride-68 pad)
//   p_base : 107008 .. 111104  P tile 32x64 f16, swizzled
//   m/l/c  : 111104 .. 111488  softmax state
template<bool WS16>
__global__ __launch_bounds__(NT_, 2)
void attn_fused(const float* __restrict__ hid,
                const float* __restrict__ enc,
                const _Float16* __restrict__ encH,
                float* __restrict__ out) {
  __shared__ __attribute__((aligned(16))) char smem[111488];
  char*  const q_base = smem;
  char*  const stg0   = smem + 65536;
  char*  const stg1   = smem + 81920;
  float* const s_lds  = (float*)(smem + 98304);
  char*  const p_base = smem + 107008;
  float* const m_lds  = (float*)(smem + 111104);
  float* const l_lds  = m_lds + 32;
  float* const c_lds  = m_lds + 64;

  const int tid  = threadIdx.x;
  const int lane = tid & 63;
  const int wid  = tid >> 6;
  const int arow = lane & 15;   // MFMA A/B m/n index
  const int agrp = lane >> 4;   // MFMA k-group
  const int b    = blockIdx.x;
  const int q0   = blockIdx.y * QB_;

  if (tid < 32) { m_lds[tid] = -__builtin_inff(); l_lds[tid] = 0.0f; }

  // ---- stage Q (32 x 1024) fp32 -> f16, swizzled ----
  {
    const float* qsrc = hid + ((size_t)b * TQ_ + q0) * DH_;
    #pragma unroll
    for (int k = 0; k < 16; ++k) {
      int i = tid + k * NT_;            // 8192 float4 units
      int q = i >> 8;
      int h = (i & 255) * 4;
      float4 v = *(const float4*)(qsrc + (size_t)q * DH_ + h);
      int byte = (q * 2048 + h * 2) ^ ((q & 7) << 4);
      *(uint32_t*)(q_base + byte)     = pack_h2(v.x, v.y);
      *(uint32_t*)(q_base + byte + 4) = pack_h2(v.z, v.w);
    }
  }
  __syncthreads();

  f32x4 o_acc[8][2];
  #pragma unroll
  for (int c = 0; c < 8; ++c) {
    o_acc[c][0] = {};
    o_acc[c][1] = {};
  }

  const int qt = wid >> 2;  // q sub-tile for QK^T (0..1)
  const int ss = wid & 3;   // s sub-tile for QK^T (0..3)
  const size_t enc_b = (size_t)b * TS_ * DH_;

  for (int st = 0; st < TS_ / SB_; ++st) {
    const int s0 = st * SB_;

    // ================= QK^T =================
    auto stageK = [&](int dc, char* buf) {
      if constexpr (WS16) {
        const _Float16* ks = encH + enc_b + (size_t)s0 * DH_ + dc * 128;
        #pragma unroll
        for (int k = 0; k < 2; ++k) {
          int u = tid + k * NT_;        // 1024 units of 8 f16
          int s = u >> 4, dl = (u & 15) * 8;
          f16x8 v = *(const f16x8*)(ks + (size_t)s * DH_ + dl);
          *(f16x8*)(buf + ((s * 256 + dl * 2) ^ ((s & 7) << 4))) = v;
        }
      } else {
        const float* ks = enc + enc_b + (size_t)s0 * DH_ + dc * 128;
        #pragma unroll
        for (int k = 0; k < 4; ++k) {
          int i = tid + k * NT_;        // 2048 float4 units
          int s = i >> 5, dl = (i & 31) * 4;
          float4 v = *(const float4*)(ks + (size_t)s * DH_ + dl);
          int byte = (s * 256 + dl * 2) ^ ((s & 7) << 4);
          *(uint32_t*)(buf + byte)     = pack_h2(v.x, v.y);
          *(uint32_t*)(buf + byte + 4) = pack_h2(v.z, v.w);
        }
      }
    };

    f32x4 s_acc = {};
    stageK(0, stg0);
    __syncthreads();
    for (int dc = 0; dc < 8; ++dc) {
      char* cur = (dc & 1) ? stg1 : stg0;
      if (dc < 7) stageK(dc + 1, (dc & 1) ? stg0 : stg1);
      #pragma unroll
      for (int ks2 = 0; ks2 < 4; ++ks2) {
        int d  = ks2 * 32 + agrp * 8;
        int qq = qt * 16 + arow;
        f16x8 af = *(const f16x8*)(q_base +
            ((qq * 2048 + (dc * 128 + d) * 2) ^ ((qq & 7) << 4)));
        int sr = ss * 16 + arow;
        f16x8 bf = *(const f16x8*)(cur +
            ((sr * 256 + d * 2) ^ ((sr & 7) << 4)));
        s_acc = __builtin_amdgcn_mfma_f32_16x16x32_f16(af, bf, s_acc, 0, 0, 0);
      }
      __syncthreads();
    }

    // write S tile (C layout: row = agrp*4+i, col = arow)
    {
      int sc2 = ss * 16 + arow;
      #pragma unroll
      for (int i = 0; i < 4; ++i)
        s_lds[(qt * 16 + agrp * 4 + i) * 68 + sc2] = s_acc[i];
    }
    __syncthreads();

    // ================= online softmax over this s-tile =================
    {
      int r = tid >> 4, ci = tid & 15;  // 32 rows x 16 threads, 4 contiguous cols each
      float4 v = *(const float4*)(s_lds + r * 68 + ci * 4);
      float mx = fmaxf(fmaxf(v.x, v.y), fmaxf(v.z, v.w));
      #pragma unroll
      for (int o = 8; o; o >>= 1) mx = fmaxf(mx, __shfl_xor(mx, o));
      float mprev = m_lds[r];
      float mnew  = fmaxf(mprev, mx);
      float p0 = __expf(v.x - mnew), p1 = __expf(v.y - mnew);
      float p2 = __expf(v.z - mnew), p3 = __expf(v.w - mnew);
      float ps = (p0 + p1) + (p2 + p3);
      #pragma unroll
      for (int o = 8; o; o >>= 1) ps += __shfl_xor(ps, o);
      float scf = __expf(mprev - mnew);
      if (ci == 0) { m_lds[r] = mnew; l_lds[r] = l_lds[r] * scf + ps; c_lds[r] = scf; }
      f16x4 pw;
      pw[0] = (_Float16)p0; pw[1] = (_Float16)p1;
      pw[2] = (_Float16)p2; pw[3] = (_Float16)p3;
      *(f16x4*)(p_base + ((r * 128 + ci * 8) ^ ((r & 7) << 4))) = pw;
    }
    __syncthreads();

    // rescale O by exp(m_old - m_new)
    #pragma unroll
    for (int t = 0; t < 2; ++t) {
      #pragma unroll
      for (int i = 0; i < 4; ++i) {
        float scf = c_lds[t * 16 + agrp * 4 + i];
        #pragma unroll
        for (int c = 0; c < 8; ++c) o_acc[c][t][i] *= scf;
      }
    }

    // ================= PV =================
    auto stageV = [&](int hc, char* buf) {
      if constexpr (WS16) {
        const _Float16* vs = encH + enc_b + (size_t)s0 * DH_ + hc * 128;
        #pragma unroll
        for (int k = 0; k < 2; ++k) {
          int u = tid + k * NT_;        // 1024 units: 2 s-rows x 4 h
          int s = (u >> 5) * 2, hl = (u & 31) * 4;
          f16x4 r0 = *(const f16x4*)(vs + (size_t)s * DH_ + hl);
          f16x4 r1 = *(const f16x4*)(vs + (size_t)(s + 1) * DH_ + hl);
          #pragma unroll
          for (int j = 0; j < 4; ++j) {
            union { _Float16 h[2]; uint32_t u32; } pk;
            pk.h[0] = r0[j]; pk.h[1] = r1[j];
            *(uint32_t*)(buf + (((hl + j) * 128 + s * 2) ^ (((hl + j) & 7) << 4))) = pk.u32;
          }
        }
      } else {
        const float* vs = enc + enc_b + (size_t)s0 * DH_ + hc * 128;
        #pragma unroll
        for (int k = 0; k < 2; ++k) {
          int u = tid + k * NT_;
          int s = (u >> 5) * 2, hl = (u & 31) * 4;
          float4 r0 = *(const float4*)(vs + (size_t)s * DH_ + hl);
          float4 r1 = *(const float4*)(vs + (size_t)(s + 1) * DH_ + hl);
          float a0[4] = {r0.x, r0.y, r0.z, r0.w};
          float a1[4] = {r1.x, r1.y, r1.z, r1.w};
          #pragma unroll
          for (int j = 0; j < 4; ++j)
            *(uint32_t*)(buf + (((hl + j) * 128 + s * 2) ^ (((hl + j) & 7) << 4))) =
                pack_h2(a0[j], a1[j]);
        }
      }
    };

    stageV(0, stg0);
    __syncthreads();
    for (int c = 0; c < 8; ++c) {
      char* cur = (c & 1) ? stg1 : stg0;
      if (c < 7) stageV(c + 1, (c & 1) ? stg0 : stg1);
      #pragma unroll
      for (int t = 0; t < 2; ++t) {
        #pragma unroll
        for (int ks2 = 0; ks2 < 2; ++ks2) {
          int sidx = ks2 * 32 + agrp * 8;
          int qq = t * 16 + arow;
          f16x8 af = *(const f16x8*)(p_base +
              ((qq * 128 + sidx * 2) ^ ((qq & 7) << 4)));
          int hl = wid * 16 + arow;
          f16x8 bf = *(const f16x8*)(cur +
              ((hl * 128 + sidx * 2) ^ ((hl & 7) << 4)));
          o_acc[c][t] = __builtin_amdgcn_mfma_f32_16x16x32_f16(af, bf, o_acc[c][t], 0, 0, 0);
        }
      }
      __syncthreads();
    }
  }

  // ================= epilogue: O / l =================
  #pragma unroll
  for (int t = 0; t < 2; ++t) {
    #pragma unroll
    for (int i = 0; i < 4; ++i) {
      int qr = t * 16 + agrp * 4 + i;
      float inv = 1.0f / l_lds[qr];
      #pragma unroll
      for (int c = 0; c < 8; ++c) {
        out[((size_t)b * TQ_ + q0 + qr) * DH_ + c * 128 + wid * 16 + arow] =
            o_acc[c][t][i] * inv;
      }
    }
  }
}

extern "C" void kernel_launch(void* const* d_in, const int* in_sizes, int n_in,
                              void* d_out, int out_size, void* d_ws, size_t ws_size,
                              hipStream_t stream) {
  (void)in_sizes; (void)n_in; (void)out_size;
  const float* hid = (const float*)d_in[0];
  const float* enc = (const float*)d_in[1];
  float* out = (float*)d_out;

  const size_t encN = (size_t)NB_ * TS_ * DH_;   // 33554432 elements
  const bool ws16 = (ws_size >= encN * sizeof(_Float16));

  dim3 grid(NB_, TQ_ / QB_, 1);   // (batch, q-tile): batch -> XCD affinity
  dim3 block(NT_, 1, 1);

  if (ws16) {
    _Float16* encH = (_Float16*)d_ws;
    convert_f32_f16<<<dim3((unsigned)(encN / 8 / 256)), dim3(256), 0, stream>>>(enc, encH);
    attn_fused<true><<<grid, block, 0, stream>>>(hid, enc, encH, out);
  } else {
    attn_fused<false><<<grid, block, 0, stream>>>(hid, enc, nullptr, out);
  }
}

// Round 2
// 954.482 us; speedup vs baseline: 1.9753x; 1.9753x over previous
//
#include <hip/hip_runtime.h>

#define NB_ 16
#define TQ_ 2048
#define TS_ 2048
#define DH_ 1024
#define QB_ 32
#define SB_ 64
#define NT_ 512

typedef _Float16 f16x8 __attribute__((ext_vector_type(8)));
typedef _Float16 f16x4 __attribute__((ext_vector_type(4)));
typedef float f32x4 __attribute__((ext_vector_type(4)));

__global__ void convert_f32_f16(const float* __restrict__ src, _Float16* __restrict__ dst) {
  size_t i = ((size_t)blockIdx.x * blockDim.x + threadIdx.x) * 8;
  float4 v0 = *(const float4*)(src + i);
  float4 v1 = *(const float4*)(src + i + 4);
  f16x8 o;
  o[0] = (_Float16)v0.x; o[1] = (_Float16)v0.y; o[2] = (_Float16)v0.z; o[3] = (_Float16)v0.w;
  o[4] = (_Float16)v1.x; o[5] = (_Float16)v1.y; o[6] = (_Float16)v1.z; o[7] = (_Float16)v1.w;
  *(f16x8*)(dst + i) = o;
}

template<bool WS16>
__device__ inline f16x8 ld8(const _Float16* __restrict__ hp, const float* __restrict__ fp, size_t idx) {
  if constexpr (WS16) {
    return *(const f16x8*)(hp + idx);
  } else {
    float4 a = *(const float4*)(fp + idx);
    float4 b = *(const float4*)(fp + idx + 4);
    f16x8 t;
    t[0] = (_Float16)a.x; t[1] = (_Float16)a.y; t[2] = (_Float16)a.z; t[3] = (_Float16)a.w;
    t[4] = (_Float16)b.x; t[5] = (_Float16)b.y; t[6] = (_Float16)b.z; t[7] = (_Float16)b.w;
    return t;
  }
}

// LDS layout (bytes):
//   vt     : 0      .. 65536   per-wave private V-transpose buffers, 8 x 8192
//            wave w: Vt[128 h][32 s] f16, byte = (h*64 + s*2) ^ (((h>>3)&7)<<4)
//   s_tiles: 65536  .. 102400  8 tiles [(sh*4+dw)][32 q][36] f32 (pad 36 -> <=2-way)
//   p_base : 102400 .. 106496  P [32 q][64 s] f16, byte = (q*128 + s*2) ^ ((q&7)<<4)
//   m/l/c  : 106496 .. 106880  softmax state
template<bool WS16>
__global__ __launch_bounds__(NT_, 2)
void attn_v2(const float* __restrict__ hid,
             const float* __restrict__ enc,
             const _Float16* __restrict__ encH,
             float* __restrict__ out) {
  __shared__ __attribute__((aligned(16))) char smem[106880];
  char*  const vt_all  = smem;
  float* const s_tiles = (float*)(smem + 65536);
  char*  const p_base  = smem + 102400;
  float* const m_lds   = (float*)(smem + 106496);
  float* const l_lds   = m_lds + 32;
  float* const c_lds   = m_lds + 64;

  const int tid  = threadIdx.x;
  const int lane = tid & 63;
  const int wid  = tid >> 6;
  const int arow = lane & 15;
  const int agrp = lane >> 4;

  // XCD-affine block mapping: XCD x serves batches 2x, 2x+1 (L2-resident slabs)
  const int bi = blockIdx.x;
  const int x  = bi & 7;
  const int j  = bi >> 3;       // 0..127
  const int r  = j >> 5;        // 0..3
  const int b  = x * 2 + (r >> 1);
  const int q0 = ((j & 31) + ((r & 1) << 5)) * QB_;

  const int dw = wid & 3;   // QK^T d-chunk (256 wide)
  const int sh = wid >> 2;  // QK^T s-half (32 wide)
  const int hw = wid;       // PV h-chunk (128 wide)

  if (tid < 32) { m_lds[tid] = -__builtin_inff(); l_lds[tid] = 0.0f; }

  // ---- Q fragments in registers: wave's 32q x 256d chunk ----
  f16x8 a_q[2][8];
  #pragma unroll
  for (int m = 0; m < 2; ++m) {
    #pragma unroll
    for (int kf = 0; kf < 8; ++kf) {
      const float* qp = hid + ((size_t)(b * TQ_ + q0 + m * 16 + arow)) * DH_
                            + dw * 256 + kf * 32 + agrp * 8;
      float4 v0 = *(const float4*)qp;
      float4 v1 = *(const float4*)(qp + 4);
      f16x8 t;
      t[0] = (_Float16)v0.x; t[1] = (_Float16)v0.y; t[2] = (_Float16)v0.z; t[3] = (_Float16)v0.w;
      t[4] = (_Float16)v1.x; t[5] = (_Float16)v1.y; t[6] = (_Float16)v1.z; t[7] = (_Float16)v1.w;
      a_q[m][kf] = t;
    }
  }

  f32x4 o_acc[2][8];
  #pragma unroll
  for (int m = 0; m < 2; ++m)
    #pragma unroll
    for (int n = 0; n < 8; ++n)
      o_acc[m][n] = {};

  char* const vt = vt_all + wid * 8192;
  const size_t enc_b = (size_t)b * TS_ * DH_;
  const int h8 = (lane & 15) * 8;       // staging h-octet
  const int spb = (lane >> 4) * 2;      // staging s-pair base

  for (int st = 0; st < TS_ / SB_; ++st) {
    const int s0 = st * SB_;

    // ---- issue PV phase-0 stage loads early (hide under QK^T) ----
    f16x8 stA[4][2];
    #pragma unroll
    for (int it = 0; it < 4; ++it) {
      size_t base = enc_b + (size_t)(s0 + it * 8 + spb) * DH_ + hw * 128 + h8;
      stA[it][0] = ld8<WS16>(encH, enc, base);
      stA[it][1] = ld8<WS16>(encH, enc, base + DH_);
    }

    // ---- QK^T: K-frags direct from global (L2-hot), partial S over d-chunk ----
    f32x4 sacc[2][2] = {{{}, {}}, {{}, {}}};
    #pragma unroll
    for (int kf = 0; kf < 8; ++kf) {
      size_t kb = enc_b + (size_t)(s0 + sh * 32 + arow) * DH_ + dw * 256 + kf * 32 + agrp * 8;
      f16x8 bf0 = ld8<WS16>(encH, enc, kb);
      f16x8 bf1 = ld8<WS16>(encH, enc, kb + (size_t)16 * DH_);
      sacc[0][0] = __builtin_amdgcn_mfma_f32_16x16x32_f16(a_q[0][kf], bf0, sacc[0][0], 0, 0, 0);
      sacc[0][1] = __builtin_amdgcn_mfma_f32_16x16x32_f16(a_q[0][kf], bf1, sacc[0][1], 0, 0, 0);
      sacc[1][0] = __builtin_amdgcn_mfma_f32_16x16x32_f16(a_q[1][kf], bf0, sacc[1][0], 0, 0, 0);
      sacc[1][1] = __builtin_amdgcn_mfma_f32_16x16x32_f16(a_q[1][kf], bf1, sacc[1][1], 0, 0, 0);
    }
    // write partial S tile (sh*4+dw): [32 q][36] f32
    {
      float* tp = s_tiles + (size_t)(sh * 4 + dw) * (32 * 36);
      #pragma unroll
      for (int m = 0; m < 2; ++m)
        #pragma unroll
        for (int n = 0; n < 2; ++n)
          #pragma unroll
          for (int i2 = 0; i2 < 4; ++i2)
            tp[(m * 16 + agrp * 4 + i2) * 36 + n * 16 + arow] = sacc[m][n][i2];
    }

    __syncthreads();  // b1: S complete

    // ---- online softmax: 512 threads over [32 q][64 s] ----
    {
      int q = tid >> 4, sq = tid & 15;
      int shh = sq >> 3, sc = (sq & 7) * 4;
      const float* basep = s_tiles + (size_t)shh * 4 * (32 * 36) + q * 36 + sc;
      f32x4 v = *(const f32x4*)basep;
      v += *(const f32x4*)(basep + 1152);
      v += *(const f32x4*)(basep + 2304);
      v += *(const f32x4*)(basep + 3456);
      float mx = fmaxf(fmaxf(v[0], v[1]), fmaxf(v[2], v[3]));
      #pragma unroll
      for (int o = 8; o; o >>= 1) mx = fmaxf(mx, __shfl_xor(mx, o));
      float mprev = m_lds[q];
      float mnew  = fmaxf(mprev, mx);
      float p0 = __expf(v[0] - mnew), p1 = __expf(v[1] - mnew);
      float p2 = __expf(v[2] - mnew), p3 = __expf(v[3] - mnew);
      float ps = (p0 + p1) + (p2 + p3);
      #pragma unroll
      for (int o = 8; o; o >>= 1) ps += __shfl_xor(ps, o);
      if (sq == 0) {
        float cf = __expf(mprev - mnew);
        m_lds[q] = mnew;
        l_lds[q] = l_lds[q] * cf + ps;
        c_lds[q] = cf;
      }
      f16x4 pw;
      pw[0] = (_Float16)p0; pw[1] = (_Float16)p1;
      pw[2] = (_Float16)p2; pw[3] = (_Float16)p3;
      *(f16x4*)(p_base + ((q * 128 + sq * 8) ^ ((q & 7) << 4))) = pw;
    }

    __syncthreads();  // b2: P + m/l/c complete

    // ---- rescale O ----
    #pragma unroll
    for (int m = 0; m < 2; ++m)
      #pragma unroll
      for (int i2 = 0; i2 < 4; ++i2) {
        float cf = c_lds[m * 16 + agrp * 4 + i2];
        #pragma unroll
        for (int n = 0; n < 8; ++n) o_acc[m][n][i2] *= cf;
      }

    // ---- PV phase 0 (s 0..31): write Vt (private, no barrier), issue ph1 loads, MFMA ----
    #pragma unroll
    for (int it = 0; it < 4; ++it) {
      int sp = it * 8 + spb;
      #pragma unroll
      for (int jj = 0; jj < 8; ++jj) {
        int hloc = h8 + jj;
        union { _Float16 h[2]; uint32_t u; } pk;
        pk.h[0] = stA[it][0][jj]; pk.h[1] = stA[it][1][jj];
        *(uint32_t*)(vt + ((hloc * 64 + sp * 2) ^ (((hloc >> 3) & 7) << 4))) = pk.u;
      }
    }
    f16x8 stB[4][2];
    #pragma unroll
    for (int it = 0; it < 4; ++it) {
      size_t base = enc_b + (size_t)(s0 + 32 + it * 8 + spb) * DH_ + hw * 128 + h8;
      stB[it][0] = ld8<WS16>(encH, enc, base);
      stB[it][1] = ld8<WS16>(encH, enc, base + DH_);
    }
    {
      f16x8 pa0 = *(const f16x8*)(p_base + (((arow) * 128 + agrp * 16) ^ ((arow & 7) << 4)));
      f16x8 pa1 = *(const f16x8*)(p_base + (((16 + arow) * 128 + agrp * 16) ^ ((arow & 7) << 4)));
      #pragma unroll
      for (int n = 0; n < 8; ++n) {
        int hloc = n * 16 + arow;
        f16x8 bv = *(const f16x8*)(vt + ((hloc * 64 + agrp * 16) ^ (((hloc >> 3) & 7) << 4)));
        o_acc[0][n] = __builtin_amdgcn_mfma_f32_16x16x32_f16(pa0, bv, o_acc[0][n], 0, 0, 0);
        o_acc[1][n] = __builtin_amdgcn_mfma_f32_16x16x32_f16(pa1, bv, o_acc[1][n], 0, 0, 0);
      }
    }

    // ---- PV phase 1 (s 32..63): overwrite Vt (same wave, DS in-order), MFMA ----
    #pragma unroll
    for (int it = 0; it < 4; ++it) {
      int sp = it * 8 + spb;
      #pragma unroll
      for (int jj = 0; jj < 8; ++jj) {
        int hloc = h8 + jj;
        union { _Float16 h[2]; uint32_t u; } pk;
        pk.h[0] = stB[it][0][jj]; pk.h[1] = stB[it][1][jj];
        *(uint32_t*)(vt + ((hloc * 64 + sp * 2) ^ (((hloc >> 3) & 7) << 4))) = pk.u;
      }
    }
    {
      f16x8 pa0 = *(const f16x8*)(p_base + (((arow) * 128 + 64 + agrp * 16) ^ ((arow & 7) << 4)));
      f16x8 pa1 = *(const f16x8*)(p_base + (((16 + arow) * 128 + 64 + agrp * 16) ^ ((arow & 7) << 4)));
      #pragma unroll
      for (int n = 0; n < 8; ++n) {
        int hloc = n * 16 + arow;
        f16x8 bv = *(const f16x8*)(vt + ((hloc * 64 + agrp * 16) ^ (((hloc >> 3) & 7) << 4)));
        o_acc[0][n] = __builtin_amdgcn_mfma_f32_16x16x32_f16(pa0, bv, o_acc[0][n], 0, 0, 0);
        o_acc[1][n] = __builtin_amdgcn_mfma_f32_16x16x32_f16(pa1, bv, o_acc[1][n], 0, 0, 0);
      }
    }
  }

  // ---- epilogue: O / l ----
  #pragma unroll
  for (int m = 0; m < 2; ++m) {
    #pragma unroll
    for (int i2 = 0; i2 < 4; ++i2) {
      int qr = m * 16 + agrp * 4 + i2;
      float inv = 1.0f / l_lds[qr];
      #pragma unroll
      for (int n = 0; n < 8; ++n) {
        out[((size_t)(b * TQ_ + q0 + qr)) * DH_ + hw * 128 + n * 16 + arow] =
            o_acc[m][n][i2] * inv;
      }
    }
  }
}

extern "C" void kernel_launch(void* const* d_in, const int* in_sizes, int n_in,
                              void* d_out, int out_size, void* d_ws, size_t ws_size,
                              hipStream_t stream) {
  (void)in_sizes; (void)n_in; (void)out_size;
  const float* hid = (const float*)d_in[0];
  const float* enc = (const float*)d_in[1];
  float* out = (float*)d_out;

  const size_t encN = (size_t)NB_ * TS_ * DH_;
  const bool ws16 = (ws_size >= encN * sizeof(_Float16));

  dim3 grid(NB_ * (TQ_ / QB_), 1, 1);  // 1024, XCD-affine remap inside
  dim3 block(NT_, 1, 1);

  if (ws16) {
    _Float16* encH = (_Float16*)d_ws;
    convert_f32_f16<<<dim3((unsigned)(encN / 8 / 256)), dim3(256), 0, stream>>>(enc, encH);
    attn_v2<true><<<grid, block, 0, stream>>>(hid, enc, encH, out);
  } else {
    attn_v2<false><<<grid, block, 0, stream>>>(hid, enc, nullptr, out);
  }
}